// Round 7
// baseline (4748.387 us; speedup 1.0000x reference)
//
#include <hip/hip_runtime.h>
#include <math.h>

typedef short bf16x8 __attribute__((ext_vector_type(8)));
typedef float f32x4  __attribute__((ext_vector_type(4)));

__device__ __forceinline__ float sigmf(float x){ return 1.f/(1.f+expf(-x)); }
__device__ __forceinline__ short f2bf(float f){
    unsigned u = __float_as_uint(f);
    u = (u + 0x7FFFu + ((u>>16)&1u)) >> 16;
    return (short)u;
}
__device__ __forceinline__ float bf2f(short s){
    return __uint_as_float(((unsigned)(unsigned short)s) << 16);
}

// ---------------- conv weight split into MFMA A-fragment order ----------------
__global__ void wsplit(const float* __restrict__ w, short* __restrict__ whi, short* __restrict__ wlo,
                       int Cout, int Cin, int KW, int total)
{
    int idx = blockIdx.x*256 + threadIdx.x;
    if (idx >= total) return;
    int l = idx & 63; int t = idx >> 6;
    int KST = Cin >> 5;
    int ks = t % KST; t /= KST;
    int nCoQ = Cout >> 4;
    int coQ = t % nCoQ; int kk = t / nCoQ;
    int ky = kk / KW, kx = kk % KW;
    int co = coQ*16 + (l & 15);
    int ci = ks*32 + (l >> 4)*8;
    bf16x8 h, lo;
#pragma unroll
    for (int e = 0; e < 8; ++e) {
        float wv = w[(((size_t)co*Cin + ci + e)*KW + ky)*KW + kx];
        short hb = f2bf(wv);
        h[e] = hb;
        lo[e] = f2bf(wv - bf2f(hb));
    }
    ((bf16x8*)whi)[idx] = h;
    ((bf16x8*)wlo)[idx] = lo;
}

// ---------------- lstm gate-weight split into fragment order ----------------
__global__ void wsplit_g(const float* __restrict__ w, short* __restrict__ out)
{
    int slot = blockIdx.y;
    int i = blockIdx.x*256 + threadIdx.x;
    int l = i & 63, t = i >> 6;
    int kc = t & 15, nQ = t >> 4;
    int n = nQ*16 + (l & 15);
    int k = kc*32 + (l >> 4)*8;
    const float* src = w + ((size_t)slot*1024 + n)*512 + k;
    bf16x8 h, lo;
#pragma unroll
    for (int e = 0; e < 8; ++e) {
        float wv = src[e];
        short hb = f2bf(wv);
        h[e] = hb;
        lo[e] = f2bf(wv - bf2f(hb));
    }
    short* o = out + (size_t)slot*1048576;
    ((bf16x8*)o)[i] = h;
    ((bf16x8*)(o + 524288))[i] = lo;
}

// ---------------- MFMA conv + bias + relu + maxpool ----------------
template<int KW, int PKH, int PKW, int PSW, int PAD, bool FUSE0>
__launch_bounds__(256)
__global__ void conv_mfma(const float* __restrict__ in, const short* __restrict__ wm,
                          const float* __restrict__ bias, float* __restrict__ out,
                          int Cin, int H, int W, int Cout, int Hp, int Wp, int Wel,
                          const float* __restrict__ w0, const float* __restrict__ b0)
{
    constexpr int TAPS = KW*KW;
    constexpr int SR   = PKH + KW - 1;
    constexpr int XT   = 64;
    constexpr int XTH  = 67;
    constexpr int POB  = (XT - PKW)/PSW + 1;
    __shared__ union {
        short s[2][16][XTH][8];
        float y[64][132];
    } u;
    __shared__ float w0s[640];

    const int tid  = threadIdx.x;
    const int lane = tid & 63;
    const int wid  = tid >> 6;
    const int l15  = lane & 15, l4 = lane >> 4;
    const int nCoT = Cout >> 7;
    const int b    = blockIdx.z / nCoT;
    const int ct   = blockIdx.z % nCoT;
    const int co_blk = ct << 7;
    const int hp   = blockIdx.y;
    const int px0  = blockIdx.x * POB;
    const int x0   = px0 * PSW;
    const int y0   = hp * PKH;
    const int cow  = wid >> 1;
    const int xw   = (wid & 1) * 32;
    const int KST  = Cin >> 5;
    const int nCoQ = Cout >> 4;

    if constexpr (FUSE0) {
        for (int i = tid; i < 640; i += 256) w0s[i] = (i < 576) ? w0[i] : b0[i-576];
    }

    f32x4 acc[4][2][PKH];
#pragma unroll
    for (int c = 0; c < 4; ++c)
#pragma unroll
        for (int xf = 0; xf < 2; ++xf)
#pragma unroll
            for (int r = 0; r < PKH; ++r) acc[c][xf][r] = (f32x4){0.f,0.f,0.f,0.f};

    const float* inb = FUSE0 ? (in + (size_t)b*128*512) : (in + (size_t)b*H*W*Cin);

    for (int ci0 = 0; ci0 < Cin; ci0 += 32) {
        __syncthreads();
        constexpr int ITEMS = SR*XTH*4;
        for (int it = tid; it < ITEMS; it += 256) {
            int kslot = it & 3;
            int x  = (it >> 2) % XTH;
            int r  = (it >> 2) / XTH;
            int y  = y0 - PAD + r;
            int xg = x0 - PAD + x;
            float v[8];
            if constexpr (FUSE0) {
                if (y >= 0 && y < H && xg >= 0 && xg < W) {
                    float xin[4][4];
                    int iy0 = 2*y - 1, ix0 = 2*xg - 1;
#pragma unroll
                    for (int dy = 0; dy < 4; ++dy) {
                        int iy = iy0 + dy;
                        bool oky = (iy >= 0) && (iy < 128);
#pragma unroll
                        for (int dx = 0; dx < 4; ++dx) {
                            int ix = ix0 + dx;
                            xin[dy][dx] = (oky && ix >= 0 && ix < 512) ? inb[(size_t)iy*512 + ix] : 0.f;
                        }
                    }
#pragma unroll
                    for (int c = 0; c < 8; ++c) {
                        int co = ci0 + kslot*8 + c;
                        const float* w9 = &w0s[co*9];
                        float p00=0.f,p01=0.f,p10=0.f,p11=0.f;
#pragma unroll
                        for (int ky = 0; ky < 3; ++ky)
#pragma unroll
                            for (int kx = 0; kx < 3; ++kx) {
                                float wv = w9[ky*3+kx];
                                p00 = fmaf(xin[ky  ][kx  ], wv, p00);
                                p01 = fmaf(xin[ky  ][kx+1], wv, p01);
                                p10 = fmaf(xin[ky+1][kx  ], wv, p10);
                                p11 = fmaf(xin[ky+1][kx+1], wv, p11);
                            }
                        float m = fmaxf(fmaxf(p00,p01), fmaxf(p10,p11)) + w0s[576+co];
                        v[c] = fmaxf(m, 0.f);
                    }
                } else {
#pragma unroll
                    for (int c = 0; c < 8; ++c) v[c] = 0.f;
                }
            } else {
                if (y >= 0 && y < H && xg >= 0 && xg < W) {
                    const float* p = inb + ((size_t)y*W + xg)*Cin + ci0 + kslot*8;
                    float4 a = *(const float4*)p;
                    float4 bq = *(const float4*)(p+4);
                    v[0]=a.x; v[1]=a.y; v[2]=a.z; v[3]=a.w;
                    v[4]=bq.x; v[5]=bq.y; v[6]=bq.z; v[7]=bq.w;
                } else {
#pragma unroll
                    for (int c = 0; c < 8; ++c) v[c] = 0.f;
                }
            }
            bf16x8 h8, l8;
#pragma unroll
            for (int c = 0; c < 8; ++c) {
                short hb = f2bf(v[c]);
                h8[c] = hb;
                l8[c] = f2bf(v[c] - bf2f(hb));
            }
            *(bf16x8*)&u.s[0][r*4+kslot][x][0] = h8;
            *(bf16x8*)&u.s[1][r*4+kslot][x][0] = l8;
        }
        __syncthreads();

        const int ks = ci0 >> 5;
        for (int kk = 0; kk < TAPS; ++kk) {
            const int ky = kk / KW, kx = kk % KW;
            bf16x8 ah[4], al[4];
            const size_t abase = (((size_t)kk*nCoQ + (co_blk>>4) + cow*4)*KST + ks)*512 + lane*8;
            const size_t cstr  = (size_t)KST*512;
#pragma unroll
            for (int c = 0; c < 4; ++c) {
                ah[c] = *(const bf16x8*)(wm + abase + c*cstr);
                al[c] = *(const bf16x8*)(wm + Wel + abase + c*cstr);
            }
#pragma unroll
            for (int r = 0; r < PKH; ++r) {
                const int sr = r + ky;
                bf16x8 bh[2], bl[2];
#pragma unroll
                for (int xf = 0; xf < 2; ++xf) {
                    int xcol = xw + xf*16 + l15 + kx;
                    bh[xf] = *(const bf16x8*)&u.s[0][sr*4 + l4][xcol][0];
                    bl[xf] = *(const bf16x8*)&u.s[1][sr*4 + l4][xcol][0];
                }
#pragma unroll
                for (int c = 0; c < 4; ++c)
#pragma unroll
                    for (int xf = 0; xf < 2; ++xf) {
                        acc[c][xf][r] = __builtin_amdgcn_mfma_f32_16x16x32_bf16(ah[c], bh[xf], acc[c][xf][r], 0,0,0);
                        acc[c][xf][r] = __builtin_amdgcn_mfma_f32_16x16x32_bf16(ah[c], bl[xf], acc[c][xf][r], 0,0,0);
                        acc[c][xf][r] = __builtin_amdgcn_mfma_f32_16x16x32_bf16(al[c], bh[xf], acc[c][xf][r], 0,0,0);
                    }
            }
        }
    }

    __syncthreads();
#pragma unroll
    for (int c = 0; c < 4; ++c) {
        int co_l = cow*64 + c*16 + l4*4;
        float4 b4 = *(const float4*)&bias[co_blk + co_l];
#pragma unroll
        for (int xf = 0; xf < 2; ++xf) {
            f32x4 v = acc[c][xf][0];
            if (PKH == 2) {
                f32x4 v1 = acc[c][xf][1];
                v[0]=fmaxf(v[0],v1[0]); v[1]=fmaxf(v[1],v1[1]);
                v[2]=fmaxf(v[2],v1[2]); v[3]=fmaxf(v[3],v1[3]);
            }
            v[0]+=b4.x; v[1]+=b4.y; v[2]+=b4.z; v[3]+=b4.w;
            int x = xw + xf*16 + l15;
            *(f32x4*)&u.y[x][co_l] = v;
        }
    }
    __syncthreads();
    for (int i = tid; i < POB*128; i += 256) {
        int co = i & 127, p = i >> 7;
        int x = p * PSW;
        float v = u.y[x][co];
        if (PKW == 2) v = fmaxf(v, u.y[x+1][co]);
        v = fmaxf(v, 0.f);
        int px = px0 + p;
        if (px < Wp)
            out[(((size_t)b*Hp + hp)*Wp + px)*Cout + co_blk + co] = v;
    }
}

// ---------------- MFMA split-bf16 gate GEMM ----------------
__launch_bounds__(256)
__global__ void gemm_mfma(const float* __restrict__ A, const short* __restrict__ wg,
                          const float* __restrict__ bi, const float* __restrict__ bh,
                          float* __restrict__ Cf, float* __restrict__ Cb,
                          int M, int s0)
{
    __shared__ short sa[2][4][64][8];
    const int tid = threadIdx.x;
    const int lane = tid & 63;
    const int wid = tid >> 6;
    const int l15 = lane & 15, l4 = lane >> 4;
    const int cow = wid >> 1;
    const int xw  = wid & 1;
    const int m0 = blockIdx.x * 64;
    const int n0 = blockIdx.y * 128;
    const int slot = s0 + blockIdx.z;
    const short* whi = wg + (size_t)slot * 1048576;
    const short* wlo = whi + 524288;
    float* C = blockIdx.z ? Cb : Cf;
    const float* b1 = bi + slot*1024;
    const float* b2 = bh + slot*1024;

    const int mg  = wid;
    const int pos = tid & 63;
    const int sm  = mg*16 + (pos & 15);
    const int skl = pos >> 4;
    const int gm  = m0 + sm;
    const int nQb = blockIdx.y*8 + cow*4;

    f32x4 acc[4][2];
#pragma unroll
    for (int c = 0; c < 4; ++c)
#pragma unroll
        for (int xf = 0; xf < 2; ++xf) acc[c][xf] = (f32x4){0.f,0.f,0.f,0.f};

    for (int kc = 0; kc < 16; ++kc) {
        __syncthreads();
        {
            float v[8];
            if (gm < M) {
                const float* ap = A + (size_t)gm*512 + kc*32 + skl*8;
                float4 q0 = *(const float4*)ap;
                float4 q1 = *(const float4*)(ap+4);
                v[0]=q0.x; v[1]=q0.y; v[2]=q0.z; v[3]=q0.w;
                v[4]=q1.x; v[5]=q1.y; v[6]=q1.z; v[7]=q1.w;
            } else {
#pragma unroll
                for (int e = 0; e < 8; ++e) v[e] = 0.f;
            }
            bf16x8 h8, l8;
#pragma unroll
            for (int e = 0; e < 8; ++e) {
                short hb = f2bf(v[e]);
                h8[e] = hb;
                l8[e] = f2bf(v[e] - bf2f(hb));
            }
            *(bf16x8*)&sa[0][mg][pos][0] = h8;
            *(bf16x8*)&sa[1][mg][pos][0] = l8;
        }
        __syncthreads();

        bf16x8 ah[4], al[4];
#pragma unroll
        for (int c = 0; c < 4; ++c) {
            size_t off = (((size_t)(nQb + c)*16 + kc)*64 + lane)*8;
            ah[c] = *(const bf16x8*)(whi + off);
            al[c] = *(const bf16x8*)(wlo + off);
        }
        bf16x8 bhv[2], blv[2];
#pragma unroll
        for (int xf = 0; xf < 2; ++xf) {
            bhv[xf] = *(const bf16x8*)&sa[0][xw*2+xf][lane][0];
            blv[xf] = *(const bf16x8*)&sa[1][xw*2+xf][lane][0];
        }
#pragma unroll
        for (int c = 0; c < 4; ++c)
#pragma unroll
            for (int xf = 0; xf < 2; ++xf) {
                acc[c][xf] = __builtin_amdgcn_mfma_f32_16x16x32_bf16(ah[c], bhv[xf], acc[c][xf], 0,0,0);
                acc[c][xf] = __builtin_amdgcn_mfma_f32_16x16x32_bf16(ah[c], blv[xf], acc[c][xf], 0,0,0);
                acc[c][xf] = __builtin_amdgcn_mfma_f32_16x16x32_bf16(al[c], bhv[xf], acc[c][xf], 0,0,0);
            }
    }

#pragma unroll
    for (int c = 0; c < 4; ++c) {
        int n = n0 + cow*64 + c*16 + l4*4;
        float4 bb1 = *(const float4*)&b1[n];
        float4 bb2 = *(const float4*)&b2[n];
#pragma unroll
        for (int xf = 0; xf < 2; ++xf) {
            int m = m0 + xw*32 + xf*16 + l15;
            if (m < M) {
                f32x4 a = acc[c][xf];
                float4 o;
                o.x = a[0] + bb1.x + bb2.x;
                o.y = a[1] + bb1.y + bb2.y;
                o.z = a[2] + bb1.z + bb2.z;
                o.w = a[3] + bb1.w + bb2.w;
                *(float4*)&C[(size_t)m*1024 + n] = o;
            }
        }
    }
}

// ---------------- fp32 GEMM (enc projection) ----------------
__launch_bounds__(256)
__global__ void gemm_nt(const float* __restrict__ A, const float* __restrict__ Bm,
                        const float* __restrict__ bias1, const float* __restrict__ bias2,
                        float* __restrict__ C, int M, int N, int K)
{
    __shared__ float As[16][68];
    __shared__ float Bs[16][68];
    const int tid = threadIdx.x;
    const int tx = tid & 15, ty = tid >> 4;
    const int row0 = blockIdx.y*64, col0 = blockIdx.x*64;
    float acc[4][4] = {};
    for (int k0 = 0; k0 < K; k0 += 16) {
#pragma unroll
        for (int i = 0; i < 4; ++i) {
            int e  = tid + i*256;
            int r  = e >> 4, kk = e & 15;
            int gr = row0 + r, gk = k0 + kk;
            As[kk][r] = (gr < M) ? A[(size_t)gr*K + gk] : 0.f;
            int gc = col0 + r;
            Bs[kk][r] = (gc < N) ? Bm[(size_t)gc*K + gk] : 0.f;
        }
        __syncthreads();
#pragma unroll
        for (int kk = 0; kk < 16; ++kk) {
            float av[4], bv[4];
#pragma unroll
            for (int i=0;i<4;++i) av[i] = As[kk][ty*4+i];
#pragma unroll
            for (int j=0;j<4;++j) bv[j] = Bs[kk][tx*4+j];
#pragma unroll
            for (int i=0;i<4;++i)
#pragma unroll
                for (int j=0;j<4;++j) acc[i][j] = fmaf(av[i], bv[j], acc[i][j]);
        }
        __syncthreads();
    }
#pragma unroll
    for (int i=0;i<4;++i)
#pragma unroll
        for (int j=0;j<4;++j) {
            int r = row0 + ty*4 + i, cc = col0 + tx*4 + j;
            if (r < M && cc < N) {
                float v = acc[i][j];
                if (bias1) v += bias1[cc];
                if (bias2) v += bias2[cc];
                C[(size_t)r*N + cc] = v;
            }
        }
}

// ---------------- transposes / relayouts ----------------
__global__ void transpose2d(const float* __restrict__ in, float* __restrict__ out, int R, int C)
{
    int idx = blockIdx.x*256 + threadIdx.x;
    if (idx >= R*C) return;
    int r = idx / C, c = idx % C;
    out[(size_t)c*R + r] = in[idx];
}

__global__ void transpose_w4(const float* __restrict__ in, float* __restrict__ out)
{
    int idx = blockIdx.x*256 + threadIdx.x;
    if (idx >= 2048*512) return;
    int row = idx >> 9, k = idx & 511;
    int gate = row >> 9, j = row & 511;
    out[((size_t)k*512 + j)*4 + gate] = in[idx];
}

// ---------------- flags zero ----------------
__global__ void zero_flags(int* __restrict__ flags, int n)
{
    int i = blockIdx.x*256 + threadIdx.x;
    if (i < n) flags[i] = 0;
}

// ---------------- LSTM spin scan v2: LDS weights + 2-chain pipelining + relaxed flags ----------------
// grid (8 jsplit, 2 bpair, 2 dir), 256 threads. Each block: j-slice of 32, two chains of 4 batches.
// LDS: w fp32 [256k][32j][4g] 128KB + hcur[256][4] 4KB + parts[4g][4b][8ks][32j] 16KB = 148KB -> 1 blk/CU
__launch_bounds__(256)
__global__ void lstm_spin(const float* __restrict__ xgf, const float* __restrict__ xgb,
                          const float* __restrict__ whh, float* __restrict__ hout,
                          float* __restrict__ hx, int* __restrict__ flags,
                          int T, int s0)
{
    __shared__ float wlds[32768];    // [k][jl][g]
    __shared__ float hcur[1024];     // [k][b]
    __shared__ float parts[4096];    // [g][b][ks][jl]
    const int tid = threadIdx.x;
    const int jq = blockIdx.x, bp = blockIdx.y, dir = blockIdx.z;
    const int j0 = jq*32;
    const float* W = whh + (size_t)(s0 + dir)*262144;   // [1024 g][256 k]

    for (int idx = tid; idx < 32768; idx += 256) {
        int k = idx & 255, r = idx >> 8;
        int jl = r & 31, g = r >> 5;
        wlds[(k*32 + jl)*4 + g] = W[((size_t)g*256 + j0 + jl)*256 + k];
    }
    const float* xg = dir ? xgb : xgf;
    const int jl_c = tid & 31, b_c = (tid >> 5) & 3;   // cell mapping (tid<128)
    const int ks = tid >> 5, jl = tid & 31;            // matvec mapping
    float cc[2] = {0.f, 0.f};
    __syncthreads();

    for (int s = 0; s < T; ++s) {
        const int t = dir ? (T-1-s) : s;
#pragma unroll
        for (int c = 0; c < 2; ++c) {
            const int bg = bp*2 + c;
            const int b0 = bg*4;
            float* hxg = hx + (size_t)(dir*4 + bg)*2048;
            int* flg = flags + (dir*4 + bg)*61;
            float xgv0=0.f, xgv1=0.f, xgv2=0.f, xgv3=0.f;
            if (tid < 128) {
                const float* xr = xg + ((size_t)(b0 + b_c)*T + t)*1024 + (j0 + jl_c);
                xgv0 = xr[0]; xgv1 = xr[256]; xgv2 = xr[512]; xgv3 = xr[768];
            }
            if (s == 0) {
                for (int i = tid; i < 1024; i += 256) hcur[i] = 0.f;
            } else {
                int* fp = flg + (s-1);
                // RELAXED poll: the sc-coherent atomic load always reads the coherence
                // point (no per-poll cache invalidate as ACQUIRE would emit).
                while (__hip_atomic_load(fp, __ATOMIC_RELAXED, __HIP_MEMORY_SCOPE_AGENT) < 8)
                    __builtin_amdgcn_s_sleep(1);
                const float* hsrc = hxg + ((s-1)&1)*1024 + tid*4;
                float v0 = __hip_atomic_load(hsrc+0, __ATOMIC_RELAXED, __HIP_MEMORY_SCOPE_AGENT);
                float v1 = __hip_atomic_load(hsrc+1, __ATOMIC_RELAXED, __HIP_MEMORY_SCOPE_AGENT);
                float v2 = __hip_atomic_load(hsrc+2, __ATOMIC_RELAXED, __HIP_MEMORY_SCOPE_AGENT);
                float v3 = __hip_atomic_load(hsrc+3, __ATOMIC_RELAXED, __HIP_MEMORY_SCOPE_AGENT);
                hcur[tid*4+0]=v0; hcur[tid*4+1]=v1; hcur[tid*4+2]=v2; hcur[tid*4+3]=v3;
            }
            __syncthreads();

            // matvec: thread (ks,jl): 32 k x 4 gates x 4 batches
            float a[4][4];
#pragma unroll
            for (int g = 0; g < 4; ++g)
#pragma unroll
                for (int b = 0; b < 4; ++b) a[g][b] = 0.f;
            for (int kk = 0; kk < 32; ++kk) {
                int k = ks*32 + kk;
                float4 wv = *(const float4*)&wlds[(k*32 + jl)*4];
                float4 hv = *(const float4*)&hcur[k*4];
                a[0][0] = fmaf(wv.x, hv.x, a[0][0]); a[0][1] = fmaf(wv.x, hv.y, a[0][1]);
                a[0][2] = fmaf(wv.x, hv.z, a[0][2]); a[0][3] = fmaf(wv.x, hv.w, a[0][3]);
                a[1][0] = fmaf(wv.y, hv.x, a[1][0]); a[1][1] = fmaf(wv.y, hv.y, a[1][1]);
                a[1][2] = fmaf(wv.y, hv.z, a[1][2]); a[1][3] = fmaf(wv.y, hv.w, a[1][3]);
                a[2][0] = fmaf(wv.z, hv.x, a[2][0]); a[2][1] = fmaf(wv.z, hv.y, a[2][1]);
                a[2][2] = fmaf(wv.z, hv.z, a[2][2]); a[2][3] = fmaf(wv.z, hv.w, a[2][3]);
                a[3][0] = fmaf(wv.w, hv.x, a[3][0]); a[3][1] = fmaf(wv.w, hv.y, a[3][1]);
                a[3][2] = fmaf(wv.w, hv.z, a[3][2]); a[3][3] = fmaf(wv.w, hv.w, a[3][3]);
            }
#pragma unroll
            for (int g = 0; g < 4; ++g)
#pragma unroll
                for (int b = 0; b < 4; ++b)
                    parts[((g*4 + b)*8 + ks)*32 + jl] = a[g][b];
            __syncthreads();

            if (tid < 128) {
                float gi = xgv0, gf = xgv1, gg = xgv2, go = xgv3;
#pragma unroll
                for (int k2 = 0; k2 < 8; ++k2) {
                    gi += parts[((0*4 + b_c)*8 + k2)*32 + jl_c];
                    gf += parts[((1*4 + b_c)*8 + k2)*32 + jl_c];
                    gg += parts[((2*4 + b_c)*8 + k2)*32 + jl_c];
                    go += parts[((3*4 + b_c)*8 + k2)*32 + jl_c];
                }
                cc[c] = sigmf(gf)*cc[c] + sigmf(gi)*tanhf(gg);
                float h = sigmf(go)*tanhf(cc[c]);
                hout[((size_t)(b0 + b_c)*T + t)*512 + dir*256 + j0 + jl_c] = h;
                __hip_atomic_store(hxg + (s&1)*1024 + (j0 + jl_c)*4 + b_c, h,
                                   __ATOMIC_RELAXED, __HIP_MEMORY_SCOPE_AGENT);
            }
            __syncthreads();   // drains vmcnt: h stores acked at coherence point before flag add
            if (tid == 0)
                __hip_atomic_fetch_add(flg + s, 1, __ATOMIC_RELAXED, __HIP_MEMORY_SCOPE_AGENT);
        }
    }
}

// ---------------- decoder: batched per-step kernels ----------------
__global__ void zero_hc(float* __restrict__ h, float* __restrict__ c)
{
    int i = blockIdx.x*256 + threadIdx.x;
    if (i < 16*512) { h[i] = 0.f; c[i] = 0.f; }
}

__launch_bounds__(256)
__global__ void dec_att(const float* __restrict__ h, const float* __restrict__ seq,
                        const float* __restrict__ enc, const float* __restrict__ dpwT,
                        const float* __restrict__ dpb, const float* __restrict__ vw,
                        float* __restrict__ ctx, int T)
{
    __shared__ float hsm[512], dec[256], sc[64];
    const int b = blockIdx.x, tid = threadIdx.x;
    hsm[tid]     = h[b*512 + tid];
    hsm[256+tid] = h[b*512 + 256 + tid];
    __syncthreads();
    float s = dpb[tid];
    for (int k = 0; k < 512; ++k) s = fmaf(hsm[k], dpwT[(size_t)k*256 + tid], s);
    dec[tid] = s;
    __syncthreads();
    {
        int t = tid >> 2, sub = tid & 3;
        float p = 0.f;
        if (t < T) {
            const float* er = enc + ((size_t)b*T + t)*256 + sub*64;
            const float* dc = dec + sub*64;
            const float* vv = vw + sub*64;
            for (int a = 0; a < 64; ++a) p = fmaf(tanhf(er[a] + dc[a]), vv[a], p);
        }
        p += __shfl_xor(p, 1, 4); p += __shfl_xor(p, 2, 4);
        if (t < T && sub == 0) sc[t] = p;
    }
    __syncthreads();
    if (tid < 64) {
        float v = (tid < T) ? sc[tid] : -1e30f;
        float m = v;
        for (int o = 1; o < 64; o <<= 1) m = fmaxf(m, __shfl_xor(m, o, 64));
        float e = (tid < T) ? expf(v - m) : 0.f;
        float ssum = e;
        for (int o = 1; o < 64; o <<= 1) ssum += __shfl_xor(ssum, o, 64);
        if (tid < T) sc[tid] = e / ssum;
    }
    __syncthreads();
#pragma unroll
    for (int half = 0; half < 2; ++half) {
        int col = tid + half*256;
        float acc = 0.f;
        const float* sr = seq + (size_t)b*T*512 + col;
        for (int t = 0; t < T; ++t) acc = fmaf(sc[t], sr[(size_t)t*512], acc);
        ctx[b*512 + col] = acc;
    }
}

__launch_bounds__(256)
__global__ void gates_part(const float* __restrict__ ctx, const float* __restrict__ h,
                           const float* __restrict__ wi4, const float* __restrict__ wh4,
                           float* __restrict__ gpart)
{
    __shared__ float xs[16][128], hsh[16][128];
    const int jt = blockIdx.x, ks = blockIdx.y;
    const int tid = threadIdx.x;
    const int jl = tid & 127, bh = tid >> 7;
    const int j = jt*128 + jl;
    const int k0 = ks*128;
    for (int idx = tid; idx < 2048; idx += 256) {
        int bb = idx >> 7, kk = idx & 127;
        xs[bb][kk]  = ctx[bb*512 + k0 + kk];
        hsh[bb][kk] = h[bb*512 + k0 + kk];
    }
    __syncthreads();
    float acc[8][4];
#pragma unroll
    for (int bi=0;bi<8;++bi)
#pragma unroll
        for (int g=0;g<4;++g) acc[bi][g]=0.f;
    const float4* wip = (const float4*)wi4 + (size_t)k0*512 + j;
    const float4* whp = (const float4*)wh4 + (size_t)k0*512 + j;
#pragma unroll 2
    for (int kk = 0; kk < 128; ++kk) {
        float4 wa = wip[(size_t)kk*512];
        float4 wb = whp[(size_t)kk*512];
#pragma unroll
        for (int bi = 0; bi < 8; ++bi) {
            int bb = bh*8 + bi;
            float xv = xs[bb][kk], hv = hsh[bb][kk];
            acc[bi][0] = fmaf(xv, wa.x, fmaf(hv, wb.x, acc[bi][0]));
            acc[bi][1] = fmaf(xv, wa.y, fmaf(hv, wb.y, acc[bi][1]));
            acc[bi][2] = fmaf(xv, wa.z, fmaf(hv, wb.z, acc[bi][2]));
            acc[bi][3] = fmaf(xv, wa.w, fmaf(hv, wb.w, acc[bi][3]));
        }
    }
    float* gp = gpart + (size_t)ks*16*2048;
#pragma unroll
    for (int bi = 0; bi < 8; ++bi)
#pragma unroll
        for (int g = 0; g < 4; ++g)
            gp[(size_t)(bh*8+bi)*2048 + j*4 + g] = acc[bi][g];
}

__launch_bounds__(512)
__global__ void cell_dense(float* __restrict__ h, float* __restrict__ c,
                           const float* __restrict__ gpart,
                           const float* __restrict__ bih, const float* __restrict__ bhh,
                           const float* __restrict__ dwT, const float* __restrict__ dnb,
                           float* __restrict__ out)
{
    __shared__ float hsh[512];
    const int b = blockIdx.x, j = threadIdx.x;
    float gi = bih[j]        + bhh[j];
    float gf = bih[512+j]    + bhh[512+j];
    float gg = bih[1024+j]   + bhh[1024+j];
    float go = bih[1536+j]   + bhh[1536+j];
#pragma unroll
    for (int ks = 0; ks < 4; ++ks) {
        float4 gp = *(const float4*)(gpart + (size_t)ks*16*2048 + (size_t)b*2048 + j*4);
        gi += gp.x; gf += gp.y; gg += gp.z; go += gp.w;
    }
    float cn = sigmf(gf)*c[b*512+j] + sigmf(gi)*tanhf(gg);
    float hn = sigmf(go)*tanhf(cn);
    c[b*512+j] = cn; h[b*512+j] = hn; hsh[j] = hn;
    __syncthreads();
    int o = j >> 2, sub = j & 3;
    float p = 0.f;
    if (o < 99) {
        const float* hk = hsh + sub*128;
        const float* wk = dwT + (size_t)sub*128*99 + o;
        for (int k = 0; k < 128; ++k) p = fmaf(hk[k], wk[(size_t)k*99], p);
    }
    p += __shfl_xor(p, 1, 4); p += __shfl_xor(p, 2, 4);
    if (o < 99 && sub == 0) out[b*99 + o] = p + dnb[o];
}

// ---------------- launch ----------------
extern "C" void kernel_launch(void* const* d_in, const int* in_sizes, int n_in,
                              void* d_out, int out_size, void* d_ws, size_t ws_size,
                              hipStream_t stream)
{
    (void)in_sizes; (void)n_in; (void)out_size; (void)ws_size;
    const float* x = (const float*)d_in[0];
    const float* convw[7]; const float* convb[7];
    for (int i = 0; i < 7; ++i) { convw[i] = (const float*)d_in[1+2*i]; convb[i] = (const float*)d_in[2+2*i]; }
    const float* lw   = (const float*)d_in[15];
    const float* lr   = (const float*)d_in[16];
    const float* lbi  = (const float*)d_in[17];
    const float* lbh  = (const float*)d_in[18];
    const float* encW = (const float*)d_in[19];
    const float* encB = (const float*)d_in[20];
    const float* dpw  = (const float*)d_in[21];
    const float* dpb  = (const float*)d_in[22];
    const float* vw   = (const float*)d_in[23];
    const float* dwih = (const float*)d_in[24];
    const float* dwhh = (const float*)d_in[25];
    const float* dbih = (const float*)d_in[26];
    const float* dbhh = (const float*)d_in[27];
    const float* dnw  = (const float*)d_in[28];
    const float* dnb  = (const float*)d_in[29];
    float* outp = (float*)d_out;

    float* ws    = (float*)d_ws;
    float* bufA  = ws;                       // 8,388,608
    float* bufB  = ws + 8388608;             // 8,388,608
    float* wscr  = ws + 16777216;            // 2,359,296 (conv weight split scratch)
    float* S0    = ws + 19136512;            // 499,712 (seq ping)
    float* SY    = ws + 19636224;            // 499,712 (seq pong)
    float* xg_f  = ws + 20135936;            // 999,424
    float* xg_b  = ws + 21135360;            // 999,424
    float* hxfl  = ws + 22134784;            // hx 16384 floats + flags 1952 ints
    float* encb  = ws + 24231936;            // 249,856
    float* dpwT  = ws + 24481792;            // 131,072
    float* dwT   = ws + 24612864;            // 50,688
    float* hbuf  = ws + 24663552;            // 8,192
    float* cbuf  = ws + 24671744;            // 8,192
    float* ctxb  = ws + 24679936;            // 8,192
    float* gpart = ws + 24688128;            // 131,072 -> end 24,819,200
    float* wihT4 = bufA;                     // decoder wih (after convs)
    float* whh2T4= bufB;                     // decoder whh (after convs)
    short* wgB   = (short*)(bufA + 1048576); // lstm gate frag split
    float* hx    = hxfl;
    int*   flags = (int*)(hxfl + 16384);

    short* whi = (short*)wscr;

    // ---- convs (L0 fused into L1) ----
    {
        int Wel = 9*(128/16)*(64/32)*512;
        wsplit<<<(Wel/8+255)/256, 256, 0, stream>>>(convw[1], whi, whi+Wel, 128, 64, 3, Wel/8);
        conv_mfma<3,2,2,2,1,true><<<dim3(4,32,16), 256, 0, stream>>>(
            x, whi, convb[1], bufA, 64,64,256,128, 32,128, Wel, convw[0], convb[0]);
    }
    {
        int Wel = 9*(256/16)*(128/32)*512;
        wsplit<<<(Wel/8+255)/256, 256, 0, stream>>>(convw[2], whi, whi+Wel, 256, 128, 3, Wel/8);
        conv_mfma<3,2,2,1,1,false><<<dim3(3,16,32), 256, 0, stream>>>(
            bufA, whi, convb[2], bufB, 128,32,128,256, 16,127, Wel, nullptr, nullptr);
    }
    {
        int Wel = 9*(512/16)*(256/32)*512;
        wsplit<<<(Wel/8+255)/256, 256, 0, stream>>>(convw[3], whi, whi+Wel, 512, 256, 3, Wel/8);
        conv_mfma<3,2,2,1,1,false><<<dim3(2,8,64), 256, 0, stream>>>(
            bufB, whi, convb[3], bufA, 256,16,127,512, 8,126, Wel, nullptr, nullptr);
    }
    {
        int Wel = 9*(512/16)*(512/32)*512;
        wsplit<<<(Wel/8+255)/256, 256, 0, stream>>>(convw[4], whi, whi+Wel, 512, 512, 3, Wel/8);
        conv_mfma<3,2,2,2,1,false><<<dim3(2,4,64), 256, 0, stream>>>(
            bufA, whi, convb[4], bufB, 512,8,126,512, 4,63, Wel, nullptr, nullptr);
    }
    {
        int Wel = 9*(512/16)*(512/32)*512;
        wsplit<<<(Wel/8+255)/256, 256, 0, stream>>>(convw[5], whi, whi+Wel, 512, 512, 3, Wel/8);
        conv_mfma<3,2,2,1,1,false><<<dim3(1,2,64), 256, 0, stream>>>(
            bufB, whi, convb[5], bufA, 512,4,63,512, 2,62, Wel, nullptr, nullptr);
    }
    {
        int Wel = 4*(512/16)*(512/32)*512;
        wsplit<<<(Wel/8+255)/256, 256, 0, stream>>>(convw[6], whi, whi+Wel, 512, 512, 2, Wel/8);
        conv_mfma<2,1,1,1,0,false><<<dim3(1,1,64), 256, 0, stream>>>(
            bufA, whi, convb[6], S0, 512,2,62,512, 1,61, Wel, nullptr, nullptr);
    }

    // ---- weight relayouts + flags init ----
    wsplit_g<<<dim3(256, 8), 256, 0, stream>>>(lw, wgB);
    zero_flags<<<8, 256, 0, stream>>>(flags, 4*2*4*61);
    transpose2d<<<(256*512 + 255)/256, 256, 0, stream>>>(dpw, dpwT, 256, 512);
    transpose_w4<<<(2048*512 + 255)/256, 256, 0, stream>>>(dwih, wihT4);
    transpose_w4<<<(2048*512 + 255)/256, 256, 0, stream>>>(dwhh, whh2T4);
    transpose2d<<<(99*512 + 255)/256, 256, 0, stream>>>(dnw, dwT, 99, 512);

    // ---- 4 BiLSTM layers ----
    const int T = 61, M = 16*T;
    float* cur = S0; float* nxt = SY;
    for (int L = 0; L < 4; ++L) {
        int s0 = 2*L;
        gemm_mfma<<<dim3(16, 8, 2), 256, 0, stream>>>(cur, wgB, lbi, lbh, xg_f, xg_b, M, s0);
        lstm_spin<<<dim3(8, 2, 2), 256, 0, stream>>>(xg_f, xg_b, lr, nxt,
                                                     hx, flags + L*488, T, s0);
        float* tmp = cur; cur = nxt; nxt = tmp;
    }
    // cur = final seq [16][61][512]

    // ---- enc projection ----
    gemm_nt<<<dim3(4, (M+63)/64), 256, 0, stream>>>(cur, encW, encB, nullptr, encb, M, 256, 512);

    // ---- decoder: 25 batched steps ----
    zero_hc<<<32, 256, 0, stream>>>(hbuf, cbuf);
    for (int step = 0; step < 25; ++step) {
        dec_att<<<16, 256, 0, stream>>>(hbuf, cur, encb, dpwT, dpb, vw, ctxb, T);
        gates_part<<<dim3(4,4), 256, 0, stream>>>(ctxb, hbuf, wihT4, whh2T4, gpart);
        cell_dense<<<16, 512, 0, stream>>>(hbuf, cbuf, gpart, dbih, dbhh, dwT, dnb,
                                           outp + (size_t)step*16*99);
    }
}